// Round 6
// baseline (247.259 us; speedup 1.0000x reference)
//
#include <hip/hip_runtime.h>

// IndexNSW R10: R9 + old-candidate graph prefetch at step start.
// One WAVE per query (B=64 blocks x 64 threads), zero barriers.
//
// Step model (measured R9 = 7100cy/step): fill+dist(5400) -> spec(300) ->
// [graph 900 || merge 700] -> fill issue. The OLD candidate (first
// unexpanded slot of the current sorted pool) is known at STEP START, so
// graph[old_cand] is prefetched ~5000cy early, hidden under the in-flight
// fill. When the pick == old_cand (p ~= (31/32)^32 ~= 36%: 32 fresh uniform
// draws all lose to the best unexpanded pool entry), the 900cy graph wait
// vanishes AND the merge runs after the fill issue (under the next fill).
// When a fresh candidate wins, the path is exactly R9 (merge under graph).
// Spec keys stay EXACT u64 (5-step reduce: halves duplicate keys), so a
// mispredict remains the all-expanded corner (~never), caught by the
// verify, which reloads graph AND re-issues the fill.
//
// Numerics: dist fmaf chain, merge key/rank/scatter, pick, and output are
// byte-identical to R4 => bit-identical trajectory (absmax 0.0 preserved).
// Merge key = (f32 bits of d)<<6 | concat idx: d>=0 so u64 order ==
// (d, idx) lexicographic == lax.top_k stable order, incl. duplicate-id ties.

#define DIMS   256
#define RDEG   32
#define EFPOOL 32
#define KOUT   10
#define NWORDS 3125     // ceil(100000 / 32)
#define INF_D  1e30f

typedef unsigned long long u64;

__global__ __launch_bounds__(64, 1) void nsw_wave_kernel(
    const float* __restrict__ query,    // [B, 256]
    const float* __restrict__ storage,  // [N, 256]
    const int*   __restrict__ graph,    // [N, 32]
    const int*   __restrict__ initial,  // [B, 32]
    float*       __restrict__ out,      // [B*10 ids as float][B*10 dists]
    int B)
{
    __shared__ unsigned int visited[NWORDS];
    __shared__ unsigned int expanded[NWORDS];
    __shared__ float4 qsh[DIMS / 4];            // query row, 64 float4
    __shared__ u64    keys[64];                 // merge keys
    __shared__ float  sc_d[EFPOOL];             // merge scatter scratch
    __shared__ int    sc_id[EFPOOL];

    const int l    = threadIdx.x;   // 0..63
    const int b    = blockIdx.x;
    const int nb   = l & 31;        // neighbor / pool slot owned (dup across halves)
    const int half = l >> 5;        // which 128-dim half this lane covers

    for (int i = l; i < NWORDS; i += 64) { visited[i] = 0u; expanded[i] = 0u; }

    // stage query row to LDS (coalesced: lane l -> float4 l)
    qsh[l] = reinterpret_cast<const float4*>(query + (size_t)b * DIMS)[l];

    float pool_d  = INF_D;   // dummy pool; first merge sorts the real entries in
    int   pool_id = 0;
    int   u       = 0;       // node expanded this step (valid from s==1)
    int   nbid    = initial[b * EFPOOL + nb];   // per-lane id of slot nb

    // reference marks all initial ids visited before the scan
    if (l < 32) atomicOr(&visited[nbid >> 5], 1u << (nbid & 31));

    float4 r[32];            // in-flight row data (constant-indexed only)

    auto issue_fill = [&](int id) {
        const float4* sp = reinterpret_cast<const float4*>(
            storage + (size_t)id * DIMS) + half * 32;
        #pragma unroll
        for (int j = 0; j < 32; ++j) r[j] = sp[j];
    };

    // merge: 64 concat elems -> sorted top-32 (byte-identical R4); reads
    // the CURRENT step's nbid/pool state, updates pool_d/pool_id.
    auto do_merge = [&](float nd_) {
        float ed  = half ? nd_  : pool_d;
        int   eid = half ? nbid : pool_id;
        u64 key = ((u64)__float_as_uint(ed) << 6) | (unsigned)l;
        keys[l] = key;
        int rank = 0;
        #pragma unroll
        for (int j = 0; j < 64; ++j)            // same addr all lanes: broadcast
            rank += (keys[j] < key) ? 1 : 0;
        if (rank < EFPOOL) { sc_d[rank] = ed; sc_id[rank] = eid; }  // ranks unique
        pool_d  = sc_d[nb];                     // in-order DS: no barrier
        pool_id = sc_id[nb];
    };

    // true pick = first unexpanded slot of merged pool (all-expanded -> 0)
    auto true_pick = [&]() -> int {
        bool unexp = !((expanded[pool_id >> 5] >> (pool_id & 31)) & 1u);
        u64 bm = __ballot(unexp && (l < 32));
        int slot = (bm == 0ull) ? 0 : (__ffsll(bm) - 1);
        return sc_id[slot];                     // uniform slot: broadcast read
    };

    issue_fill(nbid);        // prologue fill for the initial pool

    for (int s = 0; s <= EFPOOL; ++s) {        // s==0: initial pool, then 32 steps
        // ---- work hidden under the in-flight fill (LDS + 1 graph row) ----
        if (s > 0 && l == 0) expanded[u >> 5] |= 1u << (u & 31);   // sole writer

        bool fresh = true;
        if (s > 0) {
            unsigned vw = visited[nbid >> 5];   // read-all precedes OR: dup-safe
            fresh = !((vw >> (nbid & 31)) & 1u);
            if ((l < 32) && fresh) atomicOr(&visited[nbid >> 5], 1u << (nbid & 31));
        }

        // old candidate: first unexpanded slot of the CURRENT (pre-merge)
        // pool; reads expanded[] AFTER the u-mark above (program order).
        bool ounexp = !((expanded[pool_id >> 5] >> (pool_id & 31)) & 1u);
        u64  obm    = __ballot(ounexp && (l < 32));
        int  oslot  = (obm == 0ull) ? 0 : (__ffsll(obm) - 1);
        float old_d = __shfl(pool_d,  oslot, 64);
        int   old_id= __shfl(pool_id, oslot, 64);
        bool  old_ok= (obm != 0ull);
        int   gpre  = 0;
        if (s < EFPOOL)                          // prefetch old-cand graph row
            gpre = graph[(size_t)old_id * RDEG + nb];

        // ---- distance: R4's EXACT chain (compiler waits the fill here) ----
        float a0 = 0.f, a1 = 0.f, a2 = 0.f, a3 = 0.f;
        #pragma unroll
        for (int j = 0; j < 32; ++j) {
            float4 q = qsh[half * 32 + j];
            float d0 = r[j].x - q.x; a0 = fmaf(d0, d0, a0);
            float d1 = r[j].y - q.y; a1 = fmaf(d1, d1, a1);
            float d2 = r[j].z - q.z; a2 = fmaf(d2, d2, a2);
            float d3 = r[j].w - q.w; a3 = fmaf(d3, d3, a3);
        }
        float part = (a0 + a1) + (a2 + a3);
        float d  = part + __shfl_xor(part, 32, 64);   // halves share a row
        float nd = fresh ? d : INF_D;

        if (s == EFPOOL) { do_merge(nd); break; }     // final merge only

        // ---- new candidate: exact min over fresh news (5-step reduce:
        // lanes l and l^32 hold identical keys, so min-over-32 == min-over-64)
        u64 nk = fresh ? (((u64)__float_as_uint(nd) << 6) | (u64)(32 + nb))
                       : ~0ull;
        #pragma unroll
        for (int m = 1; m < 32; m <<= 1) {
            u64 o = __shfl_xor(nk, m, 64);
            nk = (o < nk) ? o : nk;
        }
        int wslot = ((int)(nk & 63) - 32) & 31;       // winner slot (if any)
        int new_id = __shfl(nbid, wslot, 64);
        u64 okey = old_ok ? (((u64)__float_as_uint(old_d) << 6) | (u64)oslot)
                          : ~0ull;
        // exact union order; old wins ties (lower concat idx). If both
        // empty, old_id == pool[0] == true pick. Wave-uniform condition.
        bool newwins = nk < okey;
        int uspec, nnbid;

        if (newwins) {
            // R9 path: graph load exposed, merge hidden under it
            uspec = new_id;
            nnbid = graph[(size_t)uspec * RDEG + nb];
            do_merge(nd);
            int utrue = true_pick();
            if (__builtin_amdgcn_readfirstlane(utrue) !=
                __builtin_amdgcn_readfirstlane(uspec))
                nnbid = graph[(size_t)utrue * RDEG + nb];   // ~never
            u = utrue; nbid = nnbid;
            issue_fill(nbid);
        } else {
            // old-cand path: graph row already in flight since step start ->
            // fill issues immediately; merge+verify run UNDER the fill
            uspec = old_id;
            nnbid = gpre;
            issue_fill(nnbid);
            do_merge(nd);
            int utrue = true_pick();
            if (__builtin_amdgcn_readfirstlane(utrue) !=
                __builtin_amdgcn_readfirstlane(uspec)) {    // ~never: redo
                nnbid = graph[(size_t)utrue * RDEG + nb];
                issue_fill(nnbid);
            }
            u = utrue; nbid = nnbid;
        }
    }

    // ---- output: pool sorted ascending; ids as float (exact < 2^24), then dists ----
    if (l < KOUT) {
        out[b * KOUT + l]            = (float)pool_id;
        out[B * KOUT + b * KOUT + l] = pool_d;
    }
}

extern "C" void kernel_launch(void* const* d_in, const int* in_sizes, int n_in,
                              void* d_out, int out_size, void* d_ws, size_t ws_size,
                              hipStream_t stream) {
    const float* query   = (const float*)d_in[0];
    const float* storage = (const float*)d_in[1];
    const int*   graph   = (const int*)d_in[2];
    const int*   initial = (const int*)d_in[3];
    float* out = (float*)d_out;

    const int B = in_sizes[0] / DIMS;   // 64

    nsw_wave_kernel<<<B, 64, 0, stream>>>(query, storage, graph, initial, out, B);
}

// Round 7
// 232.702 us; speedup vs baseline: 1.0626x; 1.0626x over previous
//
#include <hip/hip_runtime.h>

// IndexNSW R11: R9 main wave + 3 HELPER PREFETCH WAVES per block.
// Theory: the fill phase (~5400cy for 256 lines) is capped by a PER-WAVE
// outstanding-miss window (~26 lines): R4(divergent)==R7(coalesced) proves
// request grouping is irrelevant, while GEMM sustains ~44+ lines/CU with
// multiple waves => the CU can track more than one wave exposes. Helpers
// widen the window: main publishes the 32 row ids to LDS each step; each
// helper touches a disjoint third of the 256 cache lines via global_load_lds
// (16B/line, junk LDS dest, no VGPR, no waits) => lines land in L1/L2
// through the helpers' own windows; main's demand loads become L2 hits.
//  - main NEVER waits for helpers (pure accelerant; zero main-path risk)
//  - helpers are read-only; a raced publish touches a stale-but-valid row
//    (junk traffic only) => output bit-identical to R9/R4 (absmax 0.0)
//  - helpers s_waitcnt vmcnt(0) before exit (LDS-dealloc safety)
// Plus minimal branchless R10 idea: gpre = graph[old_cand] prefetched at
// step start (hidden under fill); used when old candidate wins (~36%).
// Merge key = (f32 bits of d)<<6 | concat idx: d>=0 so u64 order ==
// (d, idx) lexicographic == lax.top_k stable order, incl. duplicate-id ties.

#define DIMS   256
#define RDEG   32
#define EFPOOL 32
#define KOUT   10
#define NWORDS 3125     // ceil(100000 / 32)
#define INF_D  1e30f
#define NPUB   33       // 1 prologue + 32 steps

typedef unsigned long long u64;

__global__ __launch_bounds__(256, 1) void nsw_wave_kernel(
    const float* __restrict__ query,    // [B, 256]
    const float* __restrict__ storage,  // [N, 256]
    const int*   __restrict__ graph,    // [N, 32]
    const int*   __restrict__ initial,  // [B, 32]
    float*       __restrict__ out,      // [B*10 ids as float][B*10 dists]
    int B)
{
    __shared__ unsigned int visited[NWORDS];
    __shared__ unsigned int expanded[NWORDS];
    __shared__ float4 qsh[DIMS / 4];            // query row, 64 float4
    __shared__ u64    keys[64];                 // merge keys
    __shared__ float  sc_d[EFPOOL];             // merge scatter scratch
    __shared__ int    sc_id[EFPOOL];
    __shared__ int    xnb[EFPOOL];              // published row ids
    __shared__ int    xcnt;                     // publish counter
    __shared__ float4 touchpad[64];             // helper junk landing zone

    const int t    = threadIdx.x;   // 0..255
    const int wv   = t >> 6;        // wave 0 = main, 1..3 = helpers
    const int l    = t & 63;
    const int b    = blockIdx.x;
    const int nb   = l & 31;        // neighbor / pool slot owned (dup across halves)
    const int half = l >> 5;        // which 128-dim half this lane covers

    for (int i = t; i < NWORDS; i += 256) { visited[i] = 0u; expanded[i] = 0u; }
    if (t == 0) xcnt = 0;
    __syncthreads();                // only barrier; helpers never barrier again

    if (wv != 0) {
        // ---------------- helper waves: L2-warming touch engines ----------
        const int h     = wv - 1;               // 0..2
        const int start = h * 86;               // line partition 86/86/84
        const int count = (h == 2) ? 84 : 86;
        for (int pub = 1; pub <= NPUB; ++pub) {
            while (__hip_atomic_load(&xcnt, __ATOMIC_RELAXED,
                                     __HIP_MEMORY_SCOPE_WORKGROUP) < pub)
                __builtin_amdgcn_s_sleep(1);
            #pragma unroll
            for (int i = 0; i < 2; ++i) {
                int idx = i * 64 + l;
                if (idx < count) {
                    int line = start + idx;                 // 0..255
                    const char* src = (const char*)storage
                        + (size_t)xnb[line >> 3] * (DIMS * sizeof(float))
                        + (size_t)(line & 7) * 128;
                    __builtin_amdgcn_global_load_lds(
                        (const __attribute__((address_space(1))) void*)src,
                        (__attribute__((address_space(3))) void*)&touchpad[0],
                        16, 0, 0);
                }
            }
        }
        asm volatile("s_waitcnt vmcnt(0)" ::: "memory");    // LDS-dealloc safety
        return;
    }

    // ---------------- main wave: R9 + branchless gpre ---------------------
    qsh[l] = reinterpret_cast<const float4*>(query + (size_t)b * DIMS)[l];

    float pool_d  = INF_D;   // dummy pool; first merge sorts the real entries in
    int   pool_id = 0;
    int   u       = 0;
    int   nbid    = initial[b * EFPOOL + nb];

    // reference marks all initial ids visited before the scan
    if (l < 32) atomicOr(&visited[nbid >> 5], 1u << (nbid & 31));

    // publish prologue set, then issue prologue fill
    int pub = 1;
    if (l < 32) xnb[nb] = nbid;
    if (l == 0) __hip_atomic_store(&xcnt, pub, __ATOMIC_RELAXED,
                                   __HIP_MEMORY_SCOPE_WORKGROUP);

    float4 r[32];
    {
        const float4* sp = reinterpret_cast<const float4*>(
            storage + (size_t)nbid * DIMS) + half * 32;
        #pragma unroll
        for (int j = 0; j < 32; ++j) r[j] = sp[j];
    }

    for (int s = 0; s <= EFPOOL; ++s) {        // s==0: initial pool, then 32 steps
        // ---- work hidden under the in-flight fill ----
        if (s > 0 && l == 0) expanded[u >> 5] |= 1u << (u & 31);   // sole writer

        bool fresh = true;
        if (s > 0) {
            unsigned vw = visited[nbid >> 5];   // read-all precedes OR: dup-safe
            fresh = !((vw >> (nbid & 31)) & 1u);
            if ((l < 32) && fresh) atomicOr(&visited[nbid >> 5], 1u << (nbid & 31));
        }

        // old candidate: first unexpanded slot of the CURRENT (pre-merge) pool
        bool ounexp = !((expanded[pool_id >> 5] >> (pool_id & 31)) & 1u);
        u64  obm    = __ballot(ounexp && (l < 32));
        int  oslot  = (obm == 0ull) ? 0 : (__ffsll(obm) - 1);
        float old_d = __shfl(pool_d,  oslot, 64);
        int   old_id= __shfl(pool_id, oslot, 64);
        bool  old_ok= (obm != 0ull);
        int   gpre  = 0;
        if (s < EFPOOL)                          // old-cand graph prefetch (hidden)
            gpre = graph[(size_t)old_id * RDEG + nb];

        // ---- distance: R4's EXACT chain (compiler waits the fill here) ----
        float a0 = 0.f, a1 = 0.f, a2 = 0.f, a3 = 0.f;
        #pragma unroll
        for (int j = 0; j < 32; ++j) {
            float4 q = qsh[half * 32 + j];
            float d0 = r[j].x - q.x; a0 = fmaf(d0, d0, a0);
            float d1 = r[j].y - q.y; a1 = fmaf(d1, d1, a1);
            float d2 = r[j].z - q.z; a2 = fmaf(d2, d2, a2);
            float d3 = r[j].w - q.w; a3 = fmaf(d3, d3, a3);
        }
        float part = (a0 + a1) + (a2 + a3);
        float d  = part + __shfl_xor(part, 32, 64);   // halves share a row
        float nd = fresh ? d : INF_D;

        int nnbid = nbid;
        int uspec = 0;
        if (s < EFPOOL) {
            // new candidate: exact min over fresh news (5-step: halves dup keys)
            u64 nk = fresh ? (((u64)__float_as_uint(nd) << 6) | (u64)(32 + nb))
                           : ~0ull;
            #pragma unroll
            for (int m = 1; m < 32; m <<= 1) {
                u64 o = __shfl_xor(nk, m, 64);
                nk = (o < nk) ? o : nk;
            }
            int wslot  = ((int)(nk & 63) - 32) & 31;
            int new_id = __shfl(nbid, wslot, 64);
            u64 okey = old_ok ? (((u64)__float_as_uint(old_d) << 6) | (u64)oslot)
                              : ~0ull;
            bool newwins = nk < okey;            // exact union order; old wins ties
            uspec = newwins ? new_id : old_id;
            if (newwins) nnbid = graph[(size_t)uspec * RDEG + nb];  // exposed ~200cy
            else         nnbid = gpre;                               // already here
        }

        // ---- merge: 64 concat elems -> sorted top-32 (byte-identical R4) ----
        {
            float ed  = half ? nd   : pool_d;
            int   eid = half ? nbid : pool_id;
            u64 key = ((u64)__float_as_uint(ed) << 6) | (unsigned)l;
            keys[l] = key;
            int rank = 0;
            #pragma unroll
            for (int j = 0; j < 64; ++j)            // same addr all lanes: broadcast
                rank += (keys[j] < key) ? 1 : 0;
            if (rank < EFPOOL) { sc_d[rank] = ed; sc_id[rank] = eid; }  // ranks unique
            pool_d  = sc_d[nb];                     // in-order DS: no barrier
            pool_id = sc_id[nb];
        }

        // ---- true pick + verify; publish + issue next fill ----
        if (s < EFPOOL) {
            bool unexp = !((expanded[pool_id >> 5] >> (pool_id & 31)) & 1u);
            u64 bm = __ballot(unexp && (l < 32));
            int slot = (bm == 0ull) ? 0 : (__ffsll(bm) - 1);
            int utrue = sc_id[slot];                // uniform slot: broadcast read
            if (__builtin_amdgcn_readfirstlane(utrue) !=
                __builtin_amdgcn_readfirstlane(uspec))      // ~never (all-expanded)
                nnbid = graph[(size_t)utrue * RDEG + nb];
            u    = utrue;
            nbid = nnbid;

            ++pub;                                  // publish for helpers
            if (l < 32) xnb[nb] = nbid;
            if (l == 0) __hip_atomic_store(&xcnt, pub, __ATOMIC_RELAXED,
                                           __HIP_MEMORY_SCOPE_WORKGROUP);

            const float4* sp = reinterpret_cast<const float4*>(
                storage + (size_t)nbid * DIMS) + half * 32;
            #pragma unroll
            for (int j = 0; j < 32; ++j) r[j] = sp[j];   // next fill in flight
        }
    }

    // ---- output: pool sorted ascending; ids as float (exact < 2^24), then dists ----
    if (l < KOUT) {
        out[b * KOUT + l]            = (float)pool_id;
        out[B * KOUT + b * KOUT + l] = pool_d;
    }
}

extern "C" void kernel_launch(void* const* d_in, const int* in_sizes, int n_in,
                              void* d_out, int out_size, void* d_ws, size_t ws_size,
                              hipStream_t stream) {
    const float* query   = (const float*)d_in[0];
    const float* storage = (const float*)d_in[1];
    const int*   graph   = (const int*)d_in[2];
    const int*   initial = (const int*)d_in[3];
    float* out = (float*)d_out;

    const int B = in_sizes[0] / DIMS;   // 64

    nsw_wave_kernel<<<B, 256, 0, stream>>>(query, storage, graph, initial, out, B);
}